// Round 1
// baseline (3699.833 us; speedup 1.0000x reference)
//
#include <hip/hip_runtime.h>

typedef __attribute__((ext_vector_type(8))) short bf16x8;
typedef __attribute__((ext_vector_type(4))) float f32x4;

// ---- problem dims (fixed by reference) ----
#define BB   32      // batch
#define TT   256     // time
#define II   1024    // input features (both layers: I and 2H are 1024)
#define HH   512     // hidden
#define GG   2048    // 4H gate rows
#define BT   8192    // B*T

// ---- workspace layout (bytes) ----
#define WS_OFF_FLAGS   0ull                                   // 2 layers * 64 * 4B
#define WS_OFF_SCALES  1024ull                                // 8 * 4B (absmax bits)
#define WS_MEMSET_SPAN 2048ull
#define WS_OFF_QIH     4096ull                                // 4 * 2048*1024 bf16
#define QIH_BYTES      (4ull*GG*II*2)
#define WS_OFF_QHH     (WS_OFF_QIH + QIH_BYTES)               // 4 * [32][64][512] bf16 (permuted)
#define QHH_BYTES      (4ull*GG*HH*2)
#define WS_OFF_XBUF    (WS_OFF_QHH + QHH_BYTES)               // [8192][1024] bf16, row = t*32+b
#define XBUF_BYTES     (1ull*BT*II*2)
#define WS_OFF_YS1     (WS_OFF_XBUF + XBUF_BYTES)             // layer0 output, same layout
#define WS_OFF_HBUF    (WS_OFF_YS1 + XBUF_BYTES)              // [2 dir][2 parity][32][512] bf16
#define HBUF_BYTES     (2ull*2*BB*HH*2)
#define WS_OFF_GX      (WS_OFF_HBUF + HBUF_BYTES)             // [2 dir][256 t][2048 j][32 b]
#define GX_ELEMS       (2ull*TT*GG*BB)

__device__ __forceinline__ unsigned short f2bf(float f){
  unsigned u = __float_as_uint(f);
  u += 0x7fffu + ((u >> 16) & 1u);
  return (unsigned short)(u >> 16);
}
__device__ __forceinline__ float bf2f(unsigned short h){ return __uint_as_float(((unsigned)h) << 16); }
__device__ __forceinline__ unsigned pack2(float a, float b){ return (unsigned)f2bf(a) | ((unsigned)f2bf(b) << 16); }
__device__ __forceinline__ float sigm(float x){ return 1.0f / (1.0f + __expf(-x)); }
__device__ __forceinline__ float tanh_(float x){
  float e = __expf(-2.0f * fabsf(x));
  float t = (1.0f - e) / (1.0f + e);
  return x < 0.0f ? -t : t;
}

// ---------------- absmax per tensor (8 tensors: 4 w_ih, 4 w_hh) ----------------
__global__ __launch_bounds__(256) void k_absmax(const float* __restrict__ wih,
                                                const float* __restrict__ whh,
                                                unsigned* __restrict__ scales_raw){
  int t = blockIdx.y;
  const float* base; size_t n;
  if (t < 4){ base = wih + (size_t)t * GG * II; n = (size_t)GG * II; }
  else      { base = whh + (size_t)(t - 4) * GG * HH; n = (size_t)GG * HH; }
  size_t gtid = (size_t)blockIdx.x * 256 + threadIdx.x;  // 8192 threads
  float m = 0.0f;
  const float4* b4 = (const float4*)base;
  size_t n4 = n >> 2;
  for (size_t i = gtid; i < n4; i += 8192){
    float4 v = b4[i];
    m = fmaxf(m, fmaxf(fmaxf(fabsf(v.x), fabsf(v.y)), fmaxf(fabsf(v.z), fabsf(v.w))));
  }
  for (int off = 32; off; off >>= 1) m = fmaxf(m, __shfl_xor(m, off));
  __shared__ float red[4];
  int w = threadIdx.x >> 6, l = threadIdx.x & 63;
  if (l == 0) red[w] = m;
  __syncthreads();
  if (threadIdx.x == 0){
    m = fmaxf(fmaxf(red[0], red[1]), fmaxf(red[2], red[3]));
    atomicMax(&scales_raw[t], __float_as_uint(m));
  }
}

// ---------------- quantize w_ih -> bf16 integer q, same [2048][1024] layout ----------------
__global__ __launch_bounds__(256) void k_quant_ih(const float* __restrict__ wih,
                                                  unsigned short* __restrict__ qih,
                                                  const unsigned* __restrict__ scales_raw){
  size_t i8 = (size_t)blockIdx.x * 256 + threadIdx.x;   // 1,048,576 threads
  int t = (int)(i8 >> 18);
  size_t off = (i8 & 262143) << 3;
  float s = __uint_as_float(scales_raw[t]) / 127.0f;
  s = fmaxf(s, 1e-30f);
  const float* src = wih + ((size_t)t << 21) + off;
  float4 v0 = *(const float4*)src, v1 = *(const float4*)(src + 4);
  float q[8] = {v0.x, v0.y, v0.z, v0.w, v1.x, v1.y, v1.z, v1.w};
#pragma unroll
  for (int j = 0; j < 8; ++j) q[j] = fminf(127.0f, fmaxf(-128.0f, rintf(q[j] / s)));
  uint4 o; o.x = pack2(q[0], q[1]); o.y = pack2(q[2], q[3]); o.z = pack2(q[4], q[5]); o.w = pack2(q[6], q[7]);
  *(uint4*)(qih + ((size_t)t << 21) + off) = o;
}

// ---------------- quantize w_hh -> bf16 q in scan-permuted layout [32 bi][64 r][512 k] ----------------
// r = w*16 + hu*4 + gt  <->  source row j = gt*512 + bi*16 + w*4 + hu
__global__ __launch_bounds__(256) void k_quant_hh(const float* __restrict__ whh,
                                                  unsigned short* __restrict__ qhh,
                                                  const unsigned* __restrict__ scales_raw){
  size_t i8 = (size_t)blockIdx.x * 256 + threadIdx.x;   // 524,288 threads
  int t = (int)(i8 >> 17);
  size_t o = i8 & 131071;
  int k8 = (int)(o & 63);
  int r  = (int)((o >> 6) & 63);
  int bi = (int)(o >> 12);
  int w = r >> 4, hu = (r >> 2) & 3, gt = r & 3;
  int j = gt * 512 + bi * 16 + w * 4 + hu;
  float s = __uint_as_float(scales_raw[4 + t]) / 127.0f;
  s = fmaxf(s, 1e-30f);
  const float* src = whh + ((size_t)t << 20) + (size_t)j * HH + ((size_t)k8 << 3);
  float4 v0 = *(const float4*)src, v1 = *(const float4*)(src + 4);
  float q[8] = {v0.x, v0.y, v0.z, v0.w, v1.x, v1.y, v1.z, v1.w};
#pragma unroll
  for (int jj = 0; jj < 8; ++jj) q[jj] = fminf(127.0f, fmaxf(-128.0f, rintf(q[jj] / s)));
  uint4 ov; ov.x = pack2(q[0], q[1]); ov.y = pack2(q[2], q[3]); ov.z = pack2(q[4], q[5]); ov.w = pack2(q[6], q[7]);
  *(uint4*)(qhh + ((size_t)t << 20) + (((size_t)bi * 64 + r) << 9) + ((size_t)k8 << 3)) = ov;
}

// ---------------- x [B][T][I] f32 -> xbuf [t*32+b][I] bf16 ----------------
__global__ __launch_bounds__(256) void k_cvtx(const float* __restrict__ x,
                                              unsigned short* __restrict__ xbuf){
  size_t i8 = (size_t)blockIdx.x * 256 + threadIdx.x;   // 1,048,576 threads
  size_t row = i8 >> 7;       // t*32+b
  int c8 = (int)(i8 & 127);
  int t = (int)(row >> 5), b = (int)(row & 31);
  const float* src = x + (((size_t)b * TT + t) << 10) + ((size_t)c8 << 3);
  float4 v0 = *(const float4*)src, v1 = *(const float4*)(src + 4);
  uint4 o; o.x = pack2(v0.x, v0.y); o.y = pack2(v0.z, v0.w); o.z = pack2(v1.x, v1.y); o.w = pack2(v1.z, v1.w);
  *(uint4*)(xbuf + (row << 10) + ((size_t)c8 << 3)) = o;
}

// ---------------- gates_x GEMM: C[j][m] = s * sum_k qW[j][k] * X[m][k] ----------------
// grid (64 m-tiles, 16 j-tiles, 2 dirs), 256 threads, 128x128 tile, BK=64
__global__ __launch_bounds__(256) void k_gemm(const unsigned short* __restrict__ Aq,
                                              const unsigned short* __restrict__ X,
                                              float* __restrict__ gxf,
                                              unsigned short* __restrict__ gxh, int gx16,
                                              const unsigned* __restrict__ scales_raw, int sbase){
  int d = blockIdx.z;
  const unsigned short* A = Aq + ((size_t)d << 21);   // + d*2048*1024
  float s = __uint_as_float(scales_raw[sbase + d]) / 127.0f;
  __shared__ unsigned short As[128 * 64];
  __shared__ unsigned short Bs[128 * 64];
  int tid = threadIdx.x;
  int l = tid & 63;
  int wv = tid >> 6;
  int wr = wv >> 1, wc = wv & 1;
  int jt = blockIdx.y, mt = blockIdx.x;
  size_t arow0 = (size_t)jt * 128;
  size_t brow0 = (size_t)mt * 128;
  f32x4 acc[4][4];
  f32x4 z = {0.f, 0.f, 0.f, 0.f};
#pragma unroll
  for (int i = 0; i < 4; ++i)
#pragma unroll
    for (int j = 0; j < 4; ++j) acc[i][j] = z;

  for (int kt = 0; kt < II; kt += 64){
    __syncthreads();
#pragma unroll
    for (int p = 0; p < 4; ++p){
      int ch = p * 256 + tid;           // 0..1023
      int r = ch >> 3; int ce = (ch & 7) << 3;
      *(uint4*)&As[r * 64 + ce] = *(const uint4*)&A[(arow0 + r) * II + kt + ce];
      *(uint4*)&Bs[r * 64 + ce] = *(const uint4*)&X[(brow0 + r) * II + kt + ce];
    }
    __syncthreads();
#pragma unroll
    for (int kk = 0; kk < 64; kk += 32){
      bf16x8 a[4], b[4];
#pragma unroll
      for (int mi = 0; mi < 4; ++mi) a[mi] = *(const bf16x8*)&As[(wr * 64 + mi * 16 + (l & 15)) * 64 + kk + (l >> 4) * 8];
#pragma unroll
      for (int ni = 0; ni < 4; ++ni) b[ni] = *(const bf16x8*)&Bs[(wc * 64 + ni * 16 + (l & 15)) * 64 + kk + (l >> 4) * 8];
#pragma unroll
      for (int mi = 0; mi < 4; ++mi)
#pragma unroll
        for (int ni = 0; ni < 4; ++ni)
          acc[mi][ni] = __builtin_amdgcn_mfma_f32_16x16x32_bf16(a[mi], b[ni], acc[mi][ni], 0, 0, 0);
    }
  }
  // epilogue: gx[d][t][j][b]
  size_t gxbase = (size_t)d * ((size_t)TT * GG * BB);
#pragma unroll
  for (int mi = 0; mi < 4; ++mi){
    int j0 = jt * 128 + wr * 64 + mi * 16 + ((l >> 4) << 2);
#pragma unroll
    for (int ni = 0; ni < 4; ++ni){
      int m = mt * 128 + wc * 64 + ni * 16 + (l & 15);
      int t = m >> 5, bb = m & 31;
#pragma unroll
      for (int r = 0; r < 4; ++r){
        size_t o = gxbase + ((size_t)(t * GG + j0 + r) * BB + bb);
        float v = s * acc[mi][ni][r];
        if (gx16) gxh[o] = f2bf(v); else gxf[o] = v;
      }
    }
  }
}

// ---------------- persistent recurrent scan: 64 blocks (2 dirs x 32 hidden-slices) ----------------
__global__ __launch_bounds__(256) void k_scan(const unsigned short* __restrict__ qhh,
                                              const float* __restrict__ gxf,
                                              const unsigned short* __restrict__ gxh, int gx16,
                                              const float* __restrict__ h0,
                                              const float* __restrict__ c0,
                                              const float* __restrict__ bih,
                                              const float* __restrict__ bhh,
                                              const unsigned* __restrict__ scales_raw,
                                              unsigned short* __restrict__ hbuf,
                                              unsigned* __restrict__ flags,
                                              int layer,
                                              unsigned short* __restrict__ ys_bf16,
                                              float* __restrict__ out){
  __shared__ unsigned short Wlds[64 * 512];  // 64 KB, XOR-swizzled rows
  __shared__ unsigned short Hlds[32 * 512];  // 32 KB, XOR-swizzled rows
  int tid = threadIdx.x;
  int d = blockIdx.x >> 5, bi = blockIdx.x & 31;
  int w = tid >> 6, l = tid & 63;
  int ld = layer * 2 + d;
  float s_hh = __uint_as_float(scales_raw[4 + ld]) / 127.0f;

  // stage W slice (once): src [64 r][512 k] -> LDS swizzled
  {
    const char* src = (const char*)(qhh + ((size_t)ld << 20) + ((size_t)bi << 15));
    char* wb = (char*)Wlds;
#pragma unroll
    for (int p = 0; p < 16; ++p){
      int ch = p * 256 + tid;          // 0..4095 (16B chunks)
      int r = ch >> 6; int cb = (ch & 63) << 4;
      uint4 v = *(const uint4*)(src + r * 1024 + cb);
      *(uint4*)(wb + r * 1024 + (cb ^ ((r & 7) << 4))) = v;
    }
  }
  // stage h(0) from h0 (f32 -> bf16)
  {
    const float* h0d = h0 + ((size_t)ld << 14);
    char* hb = (char*)Hlds;
#pragma unroll
    for (int p = 0; p < 8; ++p){
      int ch = p * 256 + tid;          // 0..2047 (8-elem chunks)
      int b = ch >> 6; int c8 = ch & 63;
      const float* sp = h0d + ((size_t)b << 9) + (c8 << 3);
      float4 v0 = *(const float4*)sp, v1 = *(const float4*)(sp + 4);
      uint4 o; o.x = pack2(v0.x, v0.y); o.y = pack2(v0.z, v0.w); o.z = pack2(v1.x, v1.y); o.w = pack2(v1.z, v1.w);
      *(uint4*)(hb + b * 1024 + ((c8 << 4) ^ ((b & 7) << 4))) = o;
    }
  }

  int hu = l >> 4;
  int hidden = bi * 16 + w * 4 + hu;
  int bb0 = l & 15, bb1 = 16 + (l & 15);
  float bias[4];
#pragma unroll
  for (int gt = 0; gt < 4; ++gt){
    int j = gt * 512 + hidden;
    bias[gt] = bih[(size_t)ld * GG + j] + bhh[(size_t)ld * GG + j];
  }
  float cc[2];
  cc[0] = c0[((size_t)ld * BB + bb0) * HH + hidden];
  cc[1] = c0[((size_t)ld * BB + bb1) * HH + hidden];

  const float* gxd_f = gxf + (size_t)d * ((size_t)TT * GG * BB);
  const unsigned short* gxd_h = gxh + (size_t)d * ((size_t)TT * GG * BB);
  unsigned short* hb_d = hbuf + ((size_t)d * 2) * (BB * HH);
  unsigned* fl = flags + d * 32;

  const char* wldsb = (const char*)Wlds;
  const char* hldsb = (const char*)Hlds;
  int rA = w * 16 + (l & 15);
  int koff = (l >> 4) << 4;            // byte offset of this lane's 8-elem k-chunk

  __syncthreads();

  for (int s = 0; s < TT; ++s){
    int t = d ? (TT - 1 - s) : s;
    f32x4 acc0 = {0.f, 0.f, 0.f, 0.f}, acc1 = {0.f, 0.f, 0.f, 0.f};
#pragma unroll
    for (int kk = 0; kk < 512; kk += 32){
      bf16x8 a  = *(const bf16x8*)(wldsb + rA * 1024 + (((kk << 1) + koff) ^ ((rA & 7) << 4)));
      bf16x8 b0 = *(const bf16x8*)(hldsb + bb0 * 1024 + (((kk << 1) + koff) ^ ((bb0 & 7) << 4)));
      bf16x8 b1 = *(const bf16x8*)(hldsb + bb1 * 1024 + (((kk << 1) + koff) ^ ((bb1 & 7) << 4)));
      acc0 = __builtin_amdgcn_mfma_f32_16x16x32_bf16(a, b0, acc0, 0, 0, 0);
      acc1 = __builtin_amdgcn_mfma_f32_16x16x32_bf16(a, b1, acc1, 0, 0, 0);
    }
    // epilogue: gates -> c,h update; lane owns (batch bb, hidden) with gates i,f,g,o in regs
#pragma unroll
    for (int f = 0; f < 2; ++f){
      int bb = f ? bb1 : bb0;
      f32x4 av = f ? acc1 : acc0;
      float g[4];
#pragma unroll
      for (int gt = 0; gt < 4; ++gt){
        size_t o = (size_t)(t * GG + gt * 512 + hidden) * BB + bb;
        float gx = gx16 ? bf2f(gxd_h[o]) : gxd_f[o];
        g[gt] = av[gt] * s_hh + gx + bias[gt];
      }
      float ig = sigm(g[0]), fg = sigm(g[1]), gg = tanh_(g[2]), og = sigm(g[3]);
      float c = fg * cc[f] + ig * gg;
      cc[f] = c;
      float h = og * tanh_(c);
      hb_d[(size_t)((s + 1) & 1) * (BB * HH) + (size_t)bb * HH + hidden] = f2bf(h);
      if (layer == 0){
        ys_bf16[((size_t)(t * BB + bb) << 10) + d * 512 + hidden] = f2bf(h);
      } else {
        out[((size_t)(bb * TT + t) << 10) + d * 512 + hidden] = h;
      }
      if (s == TT - 1){
        out[8388608ull + ((size_t)ld * BB + bb) * HH + hidden] = h;   // h_n
        out[8454144ull + ((size_t)ld * BB + bb) * HH + hidden] = c;   // c_n
      }
    }
    // release: drain block stores, push to coherence point, publish flag
    __syncthreads();
    if (s < TT - 1){
      if (w == 0){
        __threadfence();
        if (tid == 0) __hip_atomic_store(&fl[bi], (unsigned)(s + 1), __ATOMIC_RELAXED, __HIP_MEMORY_SCOPE_AGENT);
        if (tid < 32){
          unsigned target = (unsigned)(s + 1);
          while (true){
            unsigned v = __hip_atomic_load(&fl[tid], __ATOMIC_RELAXED, __HIP_MEMORY_SCOPE_AGENT);
            if (__all((int)(v >= target))) break;
            __builtin_amdgcn_s_sleep(2);
          }
        }
        __threadfence();   // acquire: invalidate caches before reading peers' h
      }
      __syncthreads();
      // stage h(s+1)
      const char* srcb = (const char*)(hb_d + (size_t)((s + 1) & 1) * (BB * HH));
      char* hbw = (char*)Hlds;
#pragma unroll
      for (int p = 0; p < 8; ++p){
        int ch = p * 256 + tid;
        int b = ch >> 6; int cb = (ch & 63) << 4;
        uint4 v = *(const uint4*)(srcb + b * 1024 + cb);
        *(uint4*)(hbw + b * 1024 + (cb ^ ((b & 7) << 4))) = v;
      }
      __syncthreads();
    }
  }
}

extern "C" void kernel_launch(void* const* d_in, const int* in_sizes, int n_in,
                              void* d_out, int out_size, void* d_ws, size_t ws_size,
                              hipStream_t stream){
  if (n_in < 7) return;
  const float* x   = (const float*)d_in[0];
  const float* h0  = (const float*)d_in[1];
  const float* c0  = (const float*)d_in[2];
  const float* wih = (const float*)d_in[3];
  const float* whh = (const float*)d_in[4];
  const float* bih = (const float*)d_in[5];
  const float* bhh = (const float*)d_in[6];
  float* out = (float*)d_out;

  char* ws = (char*)d_ws;
  unsigned* flags = (unsigned*)(ws + WS_OFF_FLAGS);
  unsigned* scales = (unsigned*)(ws + WS_OFF_SCALES);
  unsigned short* qih  = (unsigned short*)(ws + WS_OFF_QIH);
  unsigned short* qhh  = (unsigned short*)(ws + WS_OFF_QHH);
  unsigned short* xbuf = (unsigned short*)(ws + WS_OFF_XBUF);
  unsigned short* ys1  = (unsigned short*)(ws + WS_OFF_YS1);
  unsigned short* hbuf = (unsigned short*)(ws + WS_OFF_HBUF);
  float* gxf = (float*)(ws + WS_OFF_GX);
  unsigned short* gxh = (unsigned short*)(ws + WS_OFF_GX);

  size_t need_f32 = WS_OFF_GX + GX_ELEMS * 4ull;
  int gx16 = (ws_size >= need_f32) ? 0 : 1;   // fall back to bf16 gates_x if ws is small

  (void)hipMemsetAsync(ws, 0, WS_MEMSET_SPAN, stream);  // flags + scales

  k_absmax<<<dim3(32, 8), 256, 0, stream>>>(wih, whh, scales);
  k_quant_ih<<<4096, 256, 0, stream>>>(wih, qih, scales);
  k_quant_hh<<<2048, 256, 0, stream>>>(whh, qhh, scales);
  k_cvtx<<<4096, 256, 0, stream>>>(x, xbuf);

  // layer 0
  k_gemm<<<dim3(64, 16, 2), 256, 0, stream>>>(qih, xbuf, gxf, gxh, gx16, scales, 0);
  k_scan<<<64, 256, 0, stream>>>(qhh, gxf, gxh, gx16, h0, c0, bih, bhh, scales,
                                 hbuf, flags, 0, ys1, out);
  // layer 1
  k_gemm<<<dim3(64, 16, 2), 256, 0, stream>>>(qih + 2ull * GG * II, ys1, gxf, gxh, gx16, scales, 2);
  k_scan<<<64, 256, 0, stream>>>(qhh, gxf, gxh, gx16, h0, c0, bih, bhh, scales,
                                 hbuf, flags + 64, 1, ys1, out);

  (void)in_sizes; (void)out_size;
}

// Round 3
// 2226.596 us; speedup vs baseline: 1.6617x; 1.6617x over previous
//
#include <hip/hip_runtime.h>

typedef __attribute__((ext_vector_type(8))) short bf16x8;
typedef __attribute__((ext_vector_type(4))) float f32x4;
typedef __attribute__((ext_vector_type(4))) unsigned u32x4;

// ---- problem dims (fixed by reference) ----
#define BB   32      // batch
#define TT   256     // time
#define II   1024    // input features (both layers: I and 2H are 1024)
#define HH   512     // hidden
#define GG   2048    // 4H gate rows
#define BT   8192    // B*T

// ---- workspace layout (bytes) ----
#define WS_OFF_FLAGS   0ull
#define WS_OFF_SCALES  1024ull
#define WS_MEMSET_SPAN 2048ull
#define WS_OFF_QIH     4096ull
#define QIH_BYTES      (4ull*GG*II*2)
#define WS_OFF_QHH     (WS_OFF_QIH + QIH_BYTES)
#define QHH_BYTES      (4ull*GG*HH*2)
#define WS_OFF_XBUF    (WS_OFF_QHH + QHH_BYTES)
#define XBUF_BYTES     (1ull*BT*II*2)
#define WS_OFF_YS1     (WS_OFF_XBUF + XBUF_BYTES)
#define WS_OFF_HBUF    (WS_OFF_YS1 + XBUF_BYTES)
#define HBUF_BYTES     (2ull*2*BB*HH*2)
#define WS_OFF_GX      (WS_OFF_HBUF + HBUF_BYTES)
#define GX_ELEMS       (2ull*TT*GG*BB)

__device__ __forceinline__ unsigned short f2bf(float f){
  unsigned u = __float_as_uint(f);
  u += 0x7fffu + ((u >> 16) & 1u);
  return (unsigned short)(u >> 16);
}
__device__ __forceinline__ float bf2f(unsigned short h){ return __uint_as_float(((unsigned)h) << 16); }
__device__ __forceinline__ unsigned pack2(float a, float b){ return (unsigned)f2bf(a) | ((unsigned)f2bf(b) << 16); }
__device__ __forceinline__ float sigm(float x){ return 1.0f / (1.0f + __expf(-x)); }
__device__ __forceinline__ float tanh_(float x){
  float e = __expf(-2.0f * fabsf(x));
  float t = (1.0f - e) / (1.0f + e);
  return x < 0.0f ? -t : t;
}

// ---- inline-asm VMEM helpers; ONLY count-free vmcnt(0) waits are used ----
__device__ __forceinline__ void st_short(void* p, unsigned v){
  asm volatile("global_store_short %0, %1, off" :: "v"(p), "v"(v) : "memory");
}
__device__ __forceinline__ void st_short_coh(void* p, unsigned v){
  asm volatile("global_store_short %0, %1, off sc0 sc1" :: "v"(p), "v"(v) : "memory");
}
__device__ __forceinline__ void st_dword(void* p, float v){
  asm volatile("global_store_dword %0, %1, off" :: "v"(p), "v"(v) : "memory");
}
__device__ __forceinline__ void ld_dword(float* d, const void* p){
  asm volatile("global_load_dword %0, %1, off" : "=v"(*d) : "v"(p));
}
__device__ __forceinline__ void ld_ushort(unsigned* d, const void* p){
  asm volatile("global_load_ushort %0, %1, off" : "=v"(*d) : "v"(p));
}
__device__ __forceinline__ void ld_b128_coh(u32x4* d, const void* p){
  asm volatile("global_load_dwordx4 %0, %1, off sc0 sc1" : "=v"(*d) : "v"(p));
}
__device__ __forceinline__ void ld_b128(bf16x8* d, const void* p){
  asm volatile("global_load_dwordx4 %0, %1, off" : "=v"(*d) : "v"(p));
}
#define WAITV0() do{ asm volatile("s_waitcnt vmcnt(0)" ::: "memory"); __builtin_amdgcn_sched_barrier(0); }while(0)
#define WAITL0() do{ asm volatile("s_waitcnt lgkmcnt(0)" ::: "memory"); __builtin_amdgcn_sched_barrier(0); }while(0)

// ---------------- absmax per tensor (8 tensors: 4 w_ih, 4 w_hh) ----------------
__global__ __launch_bounds__(256) void k_absmax(const float* __restrict__ wih,
                                                const float* __restrict__ whh,
                                                unsigned* __restrict__ scales_raw){
  int t = blockIdx.y;
  const float* base; size_t n;
  if (t < 4){ base = wih + (size_t)t * GG * II; n = (size_t)GG * II; }
  else      { base = whh + (size_t)(t - 4) * GG * HH; n = (size_t)GG * HH; }
  size_t gtid = (size_t)blockIdx.x * 256 + threadIdx.x;
  float m = 0.0f;
  const float4* b4 = (const float4*)base;
  size_t n4 = n >> 2;
  for (size_t i = gtid; i < n4; i += 8192){
    float4 v = b4[i];
    m = fmaxf(m, fmaxf(fmaxf(fabsf(v.x), fabsf(v.y)), fmaxf(fabsf(v.z), fabsf(v.w))));
  }
  for (int off = 32; off; off >>= 1) m = fmaxf(m, __shfl_xor(m, off));
  __shared__ float red[4];
  int w = threadIdx.x >> 6, l = threadIdx.x & 63;
  if (l == 0) red[w] = m;
  __syncthreads();
  if (threadIdx.x == 0){
    m = fmaxf(fmaxf(red[0], red[1]), fmaxf(red[2], red[3]));
    atomicMax(&scales_raw[t], __float_as_uint(m));
  }
}

// ---------------- quantize w_ih -> bf16 integer q, same [2048][1024] layout ----------------
__global__ __launch_bounds__(256) void k_quant_ih(const float* __restrict__ wih,
                                                  unsigned short* __restrict__ qih,
                                                  const unsigned* __restrict__ scales_raw){
  size_t i8 = (size_t)blockIdx.x * 256 + threadIdx.x;
  int t = (int)(i8 >> 18);
  size_t off = (i8 & 262143) << 3;
  float s = __uint_as_float(scales_raw[t]) / 127.0f;
  s = fmaxf(s, 1e-30f);
  const float* src = wih + ((size_t)t << 21) + off;
  float4 v0 = *(const float4*)src, v1 = *(const float4*)(src + 4);
  float q[8] = {v0.x, v0.y, v0.z, v0.w, v1.x, v1.y, v1.z, v1.w};
#pragma unroll
  for (int j = 0; j < 8; ++j) q[j] = fminf(127.0f, fmaxf(-128.0f, rintf(q[j] / s)));
  uint4 o; o.x = pack2(q[0], q[1]); o.y = pack2(q[2], q[3]); o.z = pack2(q[4], q[5]); o.w = pack2(q[6], q[7]);
  *(uint4*)(qih + ((size_t)t << 21) + off) = o;
}

// ---------------- quantize w_hh -> bf16 q in scan-permuted layout [32 bi][64 r][512 k] ----------------
__global__ __launch_bounds__(256) void k_quant_hh(const float* __restrict__ whh,
                                                  unsigned short* __restrict__ qhh,
                                                  const unsigned* __restrict__ scales_raw){
  size_t i8 = (size_t)blockIdx.x * 256 + threadIdx.x;
  int t = (int)(i8 >> 17);
  size_t o = i8 & 131071;
  int k8 = (int)(o & 63);
  int r  = (int)((o >> 6) & 63);
  int bi = (int)(o >> 12);
  int w = r >> 4, hu = (r >> 2) & 3, gt = r & 3;
  int j = gt * 512 + bi * 16 + w * 4 + hu;
  float s = __uint_as_float(scales_raw[4 + t]) / 127.0f;
  s = fmaxf(s, 1e-30f);
  const float* src = whh + ((size_t)t << 20) + (size_t)j * HH + ((size_t)k8 << 3);
  float4 v0 = *(const float4*)src, v1 = *(const float4*)(src + 4);
  float q[8] = {v0.x, v0.y, v0.z, v0.w, v1.x, v1.y, v1.z, v1.w};
#pragma unroll
  for (int jj = 0; jj < 8; ++jj) q[jj] = fminf(127.0f, fmaxf(-128.0f, rintf(q[jj] / s)));
  uint4 ov; ov.x = pack2(q[0], q[1]); ov.y = pack2(q[2], q[3]); ov.z = pack2(q[4], q[5]); ov.w = pack2(q[6], q[7]);
  *(uint4*)(qhh + ((size_t)t << 20) + (((size_t)bi * 64 + r) << 9) + ((size_t)k8 << 3)) = ov;
}

// ---------------- x [B][T][I] f32 -> xbuf [t*32+b][I] bf16 ----------------
__global__ __launch_bounds__(256) void k_cvtx(const float* __restrict__ x,
                                              unsigned short* __restrict__ xbuf){
  size_t i8 = (size_t)blockIdx.x * 256 + threadIdx.x;
  size_t row = i8 >> 7;
  int c8 = (int)(i8 & 127);
  int t = (int)(row >> 5), b = (int)(row & 31);
  const float* src = x + (((size_t)b * TT + t) << 10) + ((size_t)c8 << 3);
  float4 v0 = *(const float4*)src, v1 = *(const float4*)(src + 4);
  uint4 o; o.x = pack2(v0.x, v0.y); o.y = pack2(v0.z, v0.w); o.z = pack2(v1.x, v1.y); o.w = pack2(v1.z, v1.w);
  *(uint4*)(xbuf + (row << 10) + ((size_t)c8 << 3)) = o;
}

// ---------------- gates_x GEMM (proven in round 1) ----------------
__global__ __launch_bounds__(256) void k_gemm(const unsigned short* __restrict__ Aq,
                                              const unsigned short* __restrict__ X,
                                              float* __restrict__ gxf,
                                              unsigned short* __restrict__ gxh, int gx16,
                                              const unsigned* __restrict__ scales_raw, int sbase){
  int d = blockIdx.z;
  const unsigned short* A = Aq + ((size_t)d << 21);
  float s = __uint_as_float(scales_raw[sbase + d]) / 127.0f;
  __shared__ unsigned short As[128 * 64];
  __shared__ unsigned short Bs[128 * 64];
  int tid = threadIdx.x;
  int l = tid & 63;
  int wv = tid >> 6;
  int wr = wv >> 1, wc = wv & 1;
  int jt = blockIdx.y, mt = blockIdx.x;
  size_t arow0 = (size_t)jt * 128;
  size_t brow0 = (size_t)mt * 128;
  f32x4 acc[4][4];
  f32x4 z = {0.f, 0.f, 0.f, 0.f};
#pragma unroll
  for (int i = 0; i < 4; ++i)
#pragma unroll
    for (int j = 0; j < 4; ++j) acc[i][j] = z;

  for (int kt = 0; kt < II; kt += 64){
    __syncthreads();
#pragma unroll
    for (int p = 0; p < 4; ++p){
      int ch = p * 256 + tid;
      int r = ch >> 3; int ce = (ch & 7) << 3;
      *(uint4*)&As[r * 64 + ce] = *(const uint4*)&A[(arow0 + r) * II + kt + ce];
      *(uint4*)&Bs[r * 64 + ce] = *(const uint4*)&X[(brow0 + r) * II + kt + ce];
    }
    __syncthreads();
#pragma unroll
    for (int kk = 0; kk < 64; kk += 32){
      bf16x8 a[4], b[4];
#pragma unroll
      for (int mi = 0; mi < 4; ++mi) a[mi] = *(const bf16x8*)&As[(wr * 64 + mi * 16 + (l & 15)) * 64 + kk + (l >> 4) * 8];
#pragma unroll
      for (int ni = 0; ni < 4; ++ni) b[ni] = *(const bf16x8*)&Bs[(wc * 64 + ni * 16 + (l & 15)) * 64 + kk + (l >> 4) * 8];
#pragma unroll
      for (int mi = 0; mi < 4; ++mi)
#pragma unroll
        for (int ni = 0; ni < 4; ++ni)
          acc[mi][ni] = __builtin_amdgcn_mfma_f32_16x16x32_bf16(a[mi], b[ni], acc[mi][ni], 0, 0, 0);
    }
  }
  size_t gxbase = (size_t)d * ((size_t)TT * GG * BB);
#pragma unroll
  for (int mi = 0; mi < 4; ++mi){
    int j0 = jt * 128 + wr * 64 + mi * 16 + ((l >> 4) << 2);
#pragma unroll
    for (int ni = 0; ni < 4; ++ni){
      int m = mt * 128 + wc * 64 + ni * 16 + (l & 15);
      int t = m >> 5, bb = m & 31;
#pragma unroll
      for (int r = 0; r < 4; ++r){
        size_t o = gxbase + ((size_t)(t * GG + j0 + r) * BB + bb);
        float v = s * acc[mi][ni][r];
        if (gx16) gxh[o] = f2bf(v); else gxf[o] = v;
      }
    }
  }
}

// ---------------- persistent recurrent scan ----------------
// 64 blocks (2 dirs x 32 hidden-slices). W_hh slice in REGISTERS (16x bf16x8),
// H in 32KB swizzled LDS, exchange via sc0/sc1 write-through + relaxed flags.
// ALL manual waits are vmcnt(0) (count-free; immune to spills / compiler VMEM).
template<int GX16>
__global__ __launch_bounds__(256) void k_scan(const unsigned short* __restrict__ qhh,
                                              const float* __restrict__ gxf,
                                              const unsigned short* __restrict__ gxh,
                                              const float* __restrict__ h0,
                                              const float* __restrict__ c0,
                                              const float* __restrict__ bih,
                                              const float* __restrict__ bhh,
                                              const unsigned* __restrict__ scales_raw,
                                              unsigned short* __restrict__ hbuf,
                                              unsigned* __restrict__ flags,
                                              int layer,
                                              unsigned short* __restrict__ ys,
                                              float* __restrict__ out){
  __shared__ unsigned short Hlds[BB * HH];   // 32 KB, XOR-swizzled rows
  int tid = threadIdx.x;
  int d = blockIdx.x >> 5, bi = blockIdx.x & 31;
  int w = tid >> 6, l = tid & 63;
  int ld = layer * 2 + d;
  float s_hh = __uint_as_float(scales_raw[4 + ld]) / 127.0f;

  // stage h(0) from h0 (f32 -> bf16), swizzled
  {
    const float* h0d = h0 + ((size_t)ld << 14);
    char* hb = (char*)Hlds;
#pragma unroll
    for (int p = 0; p < 8; ++p){
      int ch = p * 256 + tid;
      int b = ch >> 6; int c8 = ch & 63;
      const float* sp = h0d + ((size_t)b << 9) + (c8 << 3);
      float4 v0 = *(const float4*)sp, v1 = *(const float4*)(sp + 4);
      u32x4 o = {pack2(v0.x, v0.y), pack2(v0.z, v0.w), pack2(v1.x, v1.y), pack2(v1.z, v1.w)};
      *(u32x4*)(hb + b * 1024 + ((c8 << 4) ^ ((b & 7) << 4))) = o;
    }
  }

  int hu = l >> 4;
  int hidden = bi * 16 + w * 4 + hu;
  int bb0 = l & 15, bb1 = 16 + (l & 15);
  float bias[4];
#pragma unroll
  for (int gt = 0; gt < 4; ++gt){
    int j = gt * 512 + hidden;
    bias[gt] = bih[(size_t)ld * GG + j] + bhh[(size_t)ld * GG + j];
  }
  float cc0 = c0[((size_t)ld * BB + bb0) * HH + hidden];
  float cc1 = c0[((size_t)ld * BB + bb1) * HH + hidden];

  // W_hh A-fragments -> registers (step-invariant), 16 x bf16x8 = 64 VGPR
  int rA = w * 16 + (l & 15);
  int koffe = (l >> 4) * 8;
  const unsigned short* qsl = qhh + ((size_t)ld << 20) + ((size_t)bi << 15);
  bf16x8 afrag[16];
#pragma unroll
  for (int kk = 0; kk < 16; ++kk)
    ld_b128(&afrag[kk], qsl + (size_t)rA * 512 + kk * 32 + koffe);

  const float* gxd_f = gxf + (size_t)d * ((size_t)TT * GG * BB);
  const unsigned short* gxd_h = gxh + (size_t)d * ((size_t)TT * GG * BB);
  unsigned short* hb_d = hbuf + ((size_t)d * 2) * (BB * HH);
  unsigned* fl = flags + d * 32;

  // prefetch gx for first step
  float gxv[8]; unsigned gxu[8];
  {
    int t0 = d ? TT - 1 : 0;
    size_t base = (size_t)t0 * GG * BB;
#pragma unroll
    for (int gt = 0; gt < 4; ++gt){
      size_t o = base + (size_t)(gt * 512 + hidden) * BB;
      if (GX16){ ld_ushort(&gxu[gt * 2],     gxd_h + o + bb0);
                 ld_ushort(&gxu[gt * 2 + 1], gxd_h + o + bb1); }
      else     { ld_dword(&gxv[gt * 2],      gxd_f + o + bb0);
                 ld_dword(&gxv[gt * 2 + 1],  gxd_f + o + bb1); }
    }
  }
  WAITV0();          // afrag + first gx resident
  __syncthreads();   // Hlds staged

  const char* hldsb = (const char*)Hlds;
  int kbyte = koffe * 2;

  for (int s = 0; s < TT; ++s){
    int t = d ? (TT - 1 - s) : s;
    // gx(s) already resident (drained by previous iteration's pre-barrier WAITV0)
    f32x4 acc0 = {0.f, 0.f, 0.f, 0.f}, acc1 = {0.f, 0.f, 0.f, 0.f};
#pragma unroll
    for (int kk = 0; kk < 16; ++kk){
      int cb = kk * 64 + kbyte;
      bf16x8 b0 = *(const bf16x8*)(hldsb + bb0 * 1024 + (cb ^ ((bb0 & 7) << 4)));
      bf16x8 b1 = *(const bf16x8*)(hldsb + bb1 * 1024 + (cb ^ ((bb1 & 7) << 4)));
      acc0 = __builtin_amdgcn_mfma_f32_16x16x32_bf16(afrag[kk], b0, acc0, 0, 0, 0);
      acc1 = __builtin_amdgcn_mfma_f32_16x16x32_bf16(afrag[kk], b1, acc1, 0, 0, 0);
    }
    float g0[4], g1[4];
#pragma unroll
    for (int gt = 0; gt < 4; ++gt){
      float gx0 = GX16 ? bf2f((unsigned short)gxu[gt * 2])     : gxv[gt * 2];
      float gx1 = GX16 ? bf2f((unsigned short)gxu[gt * 2 + 1]) : gxv[gt * 2 + 1];
      g0[gt] = acc0[gt] * s_hh + gx0 + bias[gt];
      g1[gt] = acc1[gt] * s_hh + gx1 + bias[gt];
    }
    float i0 = sigm(g0[0]), f0 = sigm(g0[1]), G0 = tanh_(g0[2]), o0 = sigm(g0[3]);
    float i1 = sigm(g1[0]), f1 = sigm(g1[1]), G1 = tanh_(g1[2]), o1 = sigm(g1[3]);
    float cn0 = f0 * cc0 + i0 * G0;  cc0 = cn0;
    float cn1 = f1 * cc1 + i1 * G1;  cc1 = cn1;
    float hx0 = o0 * tanh_(cn0);
    float hx1 = o1 * tanh_(cn1);
    unsigned yh0 = f2bf(hx0), yh1 = f2bf(hx1);

    // ys (bf16) for both layers: [t][b][1024]
    size_t ybase = (((size_t)t * BB) << 10) + (size_t)d * 512 + hidden;
    st_short(ys + ybase + ((size_t)bb0 << 10), yh0);
    st_short(ys + ybase + ((size_t)bb1 << 10), yh1);

    if (s == TT - 1){
      st_dword(out + 8388608ull + ((size_t)ld * BB + bb0) * HH + hidden, hx0);
      st_dword(out + 8388608ull + ((size_t)ld * BB + bb1) * HH + hidden, hx1);
      st_dword(out + 8454144ull + ((size_t)ld * BB + bb0) * HH + hidden, cn0);
      st_dword(out + 8454144ull + ((size_t)ld * BB + bb1) * HH + hidden, cn1);
      WAITV0();
    } else {
      // publish h(s+1): write-through coherent stores
      unsigned short* hp = hb_d + (size_t)((s + 1) & 1) * (BB * HH);
      st_short_coh(hp + (size_t)bb0 * HH + hidden, yh0);
      st_short_coh(hp + (size_t)bb1 * HH + hidden, yh1);
      WAITV0();           // stores (and ys) at the coherence point
      __syncthreads();    // F: whole block's stores done
      if (tid == 0)
        __hip_atomic_store(&fl[bi], (unsigned)(s + 1), __ATOMIC_RELAXED, __HIP_MEMORY_SCOPE_AGENT);
      // issue next-step gx prefetch NOW; it drains under the poll + h-load wait
      {
        int tn = d ? (TT - 2 - s) : (s + 1);
        size_t base = (size_t)tn * GG * BB;
#pragma unroll
        for (int gt = 0; gt < 4; ++gt){
          size_t o = base + (size_t)(gt * 512 + hidden) * BB;
          if (GX16){ ld_ushort(&gxu[gt * 2],     gxd_h + o + bb0);
                     ld_ushort(&gxu[gt * 2 + 1], gxd_h + o + bb1); }
          else     { ld_dword(&gxv[gt * 2],      gxd_f + o + bb0);
                     ld_dword(&gxv[gt * 2 + 1],  gxd_f + o + bb1); }
        }
      }
      if (tid < 32){
        unsigned target = (unsigned)(s + 1);
        while (true){
          unsigned v = __hip_atomic_load(&fl[tid], __ATOMIC_RELAXED, __HIP_MEMORY_SCOPE_AGENT);
          if (__all((int)(v >= target))) break;
          __builtin_amdgcn_s_sleep(1);
        }
      }
      __syncthreads();    // G2: all peers published
      // coherent h reload (bypass stale L1/L2)
      u32x4 hv[8];
      const char* srcb = (const char*)hp;
#pragma unroll
      for (int p = 0; p < 8; ++p){
        int ch = p * 256 + tid;
        int b = ch >> 6; int cb2 = (ch & 63) << 4;
        ld_b128_coh(&hv[p], srcb + b * 1024 + cb2);
      }
      WAITV0();           // h loads AND gx prefetch complete (count-free)
      char* hbw = (char*)Hlds;
#pragma unroll
      for (int p = 0; p < 8; ++p){
        int ch = p * 256 + tid;
        int b = ch >> 6; int cb2 = (ch & 63) << 4;
        *(u32x4*)(hbw + b * 1024 + (cb2 ^ ((b & 7) << 4))) = hv[p];
      }
      WAITL0();                          // own LDS writes visible
      __builtin_amdgcn_s_barrier();      // G3
      __builtin_amdgcn_sched_barrier(0);
    }
  }
}

// ---------------- layer-1 ys (bf16, [t][b][1024]) -> out (f32, [b][t][1024]) ----------------
__global__ __launch_bounds__(256) void k_out(const unsigned short* __restrict__ ys,
                                             float* __restrict__ out){
  size_t i4 = (size_t)blockIdx.x * 256 + threadIdx.x;
  size_t idx = i4 << 2;
  size_t row = idx >> 10; int c = (int)(idx & 1023);
  int t = (int)(row >> 5), b = (int)(row & 31);
  ushort4 v = *(const ushort4*)&ys[idx];
  float4 o = {bf2f(v.x), bf2f(v.y), bf2f(v.z), bf2f(v.w)};
  *(float4*)&out[(((size_t)b * TT + t) << 10) + c] = o;
}

extern "C" void kernel_launch(void* const* d_in, const int* in_sizes, int n_in,
                              void* d_out, int out_size, void* d_ws, size_t ws_size,
                              hipStream_t stream){
  if (n_in < 7) return;
  const float* x   = (const float*)d_in[0];
  const float* h0  = (const float*)d_in[1];
  const float* c0  = (const float*)d_in[2];
  const float* wih = (const float*)d_in[3];
  const float* whh = (const float*)d_in[4];
  const float* bih = (const float*)d_in[5];
  const float* bhh = (const float*)d_in[6];
  float* out = (float*)d_out;

  char* ws = (char*)d_ws;
  unsigned* flags = (unsigned*)(ws + WS_OFF_FLAGS);
  unsigned* scales = (unsigned*)(ws + WS_OFF_SCALES);
  unsigned short* qih  = (unsigned short*)(ws + WS_OFF_QIH);
  unsigned short* qhh  = (unsigned short*)(ws + WS_OFF_QHH);
  unsigned short* xbuf = (unsigned short*)(ws + WS_OFF_XBUF);
  unsigned short* ys1  = (unsigned short*)(ws + WS_OFF_YS1);
  unsigned short* hbuf = (unsigned short*)(ws + WS_OFF_HBUF);
  float* gxf = (float*)(ws + WS_OFF_GX);
  unsigned short* gxh = (unsigned short*)(ws + WS_OFF_GX);

  size_t need_f32 = WS_OFF_GX + GX_ELEMS * 4ull;
  int gx16 = (ws_size >= need_f32) ? 0 : 1;

  (void)hipMemsetAsync(ws, 0, WS_MEMSET_SPAN, stream);

  k_absmax<<<dim3(32, 8), 256, 0, stream>>>(wih, whh, scales);
  k_quant_ih<<<4096, 256, 0, stream>>>(wih, qih, scales);
  k_quant_hh<<<2048, 256, 0, stream>>>(whh, qhh, scales);
  k_cvtx<<<4096, 256, 0, stream>>>(x, xbuf);

  // layer 0
  k_gemm<<<dim3(64, 16, 2), 256, 0, stream>>>(qih, xbuf, gxf, gxh, gx16, scales, 0);
  if (gx16) k_scan<1><<<64, 256, 0, stream>>>(qhh, gxf, gxh, h0, c0, bih, bhh, scales, hbuf, flags, 0, ys1, out);
  else      k_scan<0><<<64, 256, 0, stream>>>(qhh, gxf, gxh, h0, c0, bih, bhh, scales, hbuf, flags, 0, ys1, out);
  // layer 1
  k_gemm<<<dim3(64, 16, 2), 256, 0, stream>>>(qih + 2ull * GG * II, ys1, gxf, gxh, gx16, scales, 2);
  if (gx16) k_scan<1><<<64, 256, 0, stream>>>(qhh, gxf, gxh, h0, c0, bih, bhh, scales, hbuf, flags + 64, 1, ys1, out);
  else      k_scan<0><<<64, 256, 0, stream>>>(qhh, gxf, gxh, h0, c0, bih, bhh, scales, hbuf, flags + 64, 1, ys1, out);

  k_out<<<8192, 256, 0, stream>>>(ys1, out);

  (void)in_sizes; (void)out_size;
}

// Round 4
// 2136.373 us; speedup vs baseline: 1.7318x; 1.0422x over previous
//
#include <hip/hip_runtime.h>

typedef __attribute__((ext_vector_type(8))) short bf16x8;
typedef __attribute__((ext_vector_type(4))) float f32x4;
typedef __attribute__((ext_vector_type(4))) unsigned u32x4;

// ---- problem dims (fixed by reference) ----
#define BB   32      // batch
#define TT   256     // time
#define II   1024    // input features (both layers: I and 2H are 1024)
#define HH   512     // hidden
#define GG   2048    // 4H gate rows
#define BT   8192    // B*T

// ---- workspace layout (bytes) ----
#define WS_OFF_FLAGS   0ull
#define WS_OFF_SCALES  1024ull
#define WS_MEMSET_SPAN 2048ull
#define WS_OFF_QIH     4096ull
#define QIH_BYTES      (4ull*GG*II*2)
#define WS_OFF_QHH     (WS_OFF_QIH + QIH_BYTES)
#define QHH_BYTES      (4ull*GG*HH*2)
#define WS_OFF_XBUF    (WS_OFF_QHH + QHH_BYTES)
#define XBUF_BYTES     (1ull*BT*II*2)
#define WS_OFF_YS1     (WS_OFF_XBUF + XBUF_BYTES)
#define WS_OFF_HFRAG   (WS_OFF_YS1 + XBUF_BYTES)   // [2 dir][2 par][2 arr][16 kk][64 lanes x 16B]
#define HFRAG_BYTES    (2ull*2*2*16*1024)          // 128 KB
#define WS_OFF_GX      (WS_OFF_HFRAG + HFRAG_BYTES)
#define GX_ELEMS       (2ull*TT*GG*BB)

__device__ __forceinline__ unsigned short f2bf(float f){
  unsigned u = __float_as_uint(f);
  u += 0x7fffu + ((u >> 16) & 1u);
  return (unsigned short)(u >> 16);
}
__device__ __forceinline__ float bf2f(unsigned short h){ return __uint_as_float(((unsigned)h) << 16); }
__device__ __forceinline__ unsigned pack2(float a, float b){ return (unsigned)f2bf(a) | ((unsigned)f2bf(b) << 16); }
__device__ __forceinline__ float sigm(float x){ return 1.0f / (1.0f + __expf(-x)); }
__device__ __forceinline__ float tanh_(float x){
  float e = __expf(-2.0f * fabsf(x));
  float t = (1.0f - e) / (1.0f + e);
  return x < 0.0f ? -t : t;
}

// ---- inline-asm VMEM helpers; ONLY count-free vmcnt(0) waits are used ----
__device__ __forceinline__ void st_dword(void* p, float v){
  asm volatile("global_store_dword %0, %1, off" :: "v"(p), "v"(v) : "memory");
}
__device__ __forceinline__ void st_b128(void* p, u32x4 v){
  asm volatile("global_store_dwordx4 %0, %1, off" :: "v"(p), "v"(v) : "memory");
}
__device__ __forceinline__ void st_b128_coh(void* p, u32x4 v){
  asm volatile("global_store_dwordx4 %0, %1, off sc0 sc1" :: "v"(p), "v"(v) : "memory");
}
__device__ __forceinline__ void ld_dword(float* d, const void* p){
  asm volatile("global_load_dword %0, %1, off" : "=v"(*d) : "v"(p));
}
__device__ __forceinline__ void ld_ushort(unsigned* d, const void* p){
  asm volatile("global_load_ushort %0, %1, off" : "=v"(*d) : "v"(p));
}
__device__ __forceinline__ void ld_frag(bf16x8* d, const void* p){
  asm volatile("global_load_dwordx4 %0, %1, off" : "=v"(*d) : "v"(p));
}
__device__ __forceinline__ void ld_frag_coh(bf16x8* d, const void* p){
  asm volatile("global_load_dwordx4 %0, %1, off sc0 sc1" : "=v"(*d) : "v"(p));
}
#define WAITV0() do{ asm volatile("s_waitcnt vmcnt(0)" ::: "memory"); __builtin_amdgcn_sched_barrier(0); }while(0)

// ---------------- absmax per tensor (8 tensors: 4 w_ih, 4 w_hh) ----------------
__global__ __launch_bounds__(256) void k_absmax(const float* __restrict__ wih,
                                                const float* __restrict__ whh,
                                                unsigned* __restrict__ scales_raw){
  int t = blockIdx.y;
  const float* base; size_t n;
  if (t < 4){ base = wih + (size_t)t * GG * II; n = (size_t)GG * II; }
  else      { base = whh + (size_t)(t - 4) * GG * HH; n = (size_t)GG * HH; }
  size_t gtid = (size_t)blockIdx.x * 256 + threadIdx.x;
  float m = 0.0f;
  const float4* b4 = (const float4*)base;
  size_t n4 = n >> 2;
  for (size_t i = gtid; i < n4; i += 8192){
    float4 v = b4[i];
    m = fmaxf(m, fmaxf(fmaxf(fabsf(v.x), fabsf(v.y)), fmaxf(fabsf(v.z), fabsf(v.w))));
  }
  for (int off = 32; off; off >>= 1) m = fmaxf(m, __shfl_xor(m, off));
  __shared__ float red[4];
  int w = threadIdx.x >> 6, l = threadIdx.x & 63;
  if (l == 0) red[w] = m;
  __syncthreads();
  if (threadIdx.x == 0){
    m = fmaxf(fmaxf(red[0], red[1]), fmaxf(red[2], red[3]));
    atomicMax(&scales_raw[t], __float_as_uint(m));
  }
}

// ---------------- quantize w_ih -> bf16 integer q, same [2048][1024] layout ----------------
__global__ __launch_bounds__(256) void k_quant_ih(const float* __restrict__ wih,
                                                  unsigned short* __restrict__ qih,
                                                  const unsigned* __restrict__ scales_raw){
  size_t i8 = (size_t)blockIdx.x * 256 + threadIdx.x;
  int t = (int)(i8 >> 18);
  size_t off = (i8 & 262143) << 3;
  float s = __uint_as_float(scales_raw[t]) / 127.0f;
  s = fmaxf(s, 1e-30f);
  const float* src = wih + ((size_t)t << 21) + off;
  float4 v0 = *(const float4*)src, v1 = *(const float4*)(src + 4);
  float q[8] = {v0.x, v0.y, v0.z, v0.w, v1.x, v1.y, v1.z, v1.w};
#pragma unroll
  for (int j = 0; j < 8; ++j) q[j] = fminf(127.0f, fmaxf(-128.0f, rintf(q[j] / s)));
  uint4 o; o.x = pack2(q[0], q[1]); o.y = pack2(q[2], q[3]); o.z = pack2(q[4], q[5]); o.w = pack2(q[6], q[7]);
  *(uint4*)(qih + ((size_t)t << 21) + off) = o;
}

// ---------------- quantize w_hh -> bf16 q in scan-permuted layout [32 bi][64 r][512 k] ----------------
__global__ __launch_bounds__(256) void k_quant_hh(const float* __restrict__ whh,
                                                  unsigned short* __restrict__ qhh,
                                                  const unsigned* __restrict__ scales_raw){
  size_t i8 = (size_t)blockIdx.x * 256 + threadIdx.x;
  int t = (int)(i8 >> 17);
  size_t o = i8 & 131071;
  int k8 = (int)(o & 63);
  int r  = (int)((o >> 6) & 63);
  int bi = (int)(o >> 12);
  int w = r >> 4, hu = (r >> 2) & 3, gt = r & 3;
  int j = gt * 512 + bi * 16 + w * 4 + hu;
  float s = __uint_as_float(scales_raw[4 + t]) / 127.0f;
  s = fmaxf(s, 1e-30f);
  const float* src = whh + ((size_t)t << 20) + (size_t)j * HH + ((size_t)k8 << 3);
  float4 v0 = *(const float4*)src, v1 = *(const float4*)(src + 4);
  float q[8] = {v0.x, v0.y, v0.z, v0.w, v1.x, v1.y, v1.z, v1.w};
#pragma unroll
  for (int jj = 0; jj < 8; ++jj) q[jj] = fminf(127.0f, fmaxf(-128.0f, rintf(q[jj] / s)));
  uint4 ov; ov.x = pack2(q[0], q[1]); ov.y = pack2(q[2], q[3]); ov.z = pack2(q[4], q[5]); ov.w = pack2(q[6], q[7]);
  *(uint4*)(qhh + ((size_t)t << 20) + (((size_t)bi * 64 + r) << 9) + ((size_t)k8 << 3)) = ov;
}

// ---------------- x [B][T][I] f32 -> xbuf [t*32+b][I] bf16 ----------------
__global__ __launch_bounds__(256) void k_cvtx(const float* __restrict__ x,
                                              unsigned short* __restrict__ xbuf){
  size_t i8 = (size_t)blockIdx.x * 256 + threadIdx.x;
  size_t row = i8 >> 7;
  int c8 = (int)(i8 & 127);
  int t = (int)(row >> 5), b = (int)(row & 31);
  const float* src = x + (((size_t)b * TT + t) << 10) + ((size_t)c8 << 3);
  float4 v0 = *(const float4*)src, v1 = *(const float4*)(src + 4);
  uint4 o; o.x = pack2(v0.x, v0.y); o.y = pack2(v0.z, v0.w); o.z = pack2(v1.x, v1.y); o.w = pack2(v1.z, v1.w);
  *(uint4*)(xbuf + (row << 10) + ((size_t)c8 << 3)) = o;
}

// ---------------- gates_x GEMM (proven in round 1) ----------------
__global__ __launch_bounds__(256) void k_gemm(const unsigned short* __restrict__ Aq,
                                              const unsigned short* __restrict__ X,
                                              float* __restrict__ gxf,
                                              unsigned short* __restrict__ gxh, int gx16,
                                              const unsigned* __restrict__ scales_raw, int sbase){
  int d = blockIdx.z;
  const unsigned short* A = Aq + ((size_t)d << 21);
  float s = __uint_as_float(scales_raw[sbase + d]) / 127.0f;
  __shared__ unsigned short As[128 * 64];
  __shared__ unsigned short Bs[128 * 64];
  int tid = threadIdx.x;
  int l = tid & 63;
  int wv = tid >> 6;
  int wr = wv >> 1, wc = wv & 1;
  int jt = blockIdx.y, mt = blockIdx.x;
  size_t arow0 = (size_t)jt * 128;
  size_t brow0 = (size_t)mt * 128;
  f32x4 acc[4][4];
  f32x4 z = {0.f, 0.f, 0.f, 0.f};
#pragma unroll
  for (int i = 0; i < 4; ++i)
#pragma unroll
    for (int j = 0; j < 4; ++j) acc[i][j] = z;

  for (int kt = 0; kt < II; kt += 64){
    __syncthreads();
#pragma unroll
    for (int p = 0; p < 4; ++p){
      int ch = p * 256 + tid;
      int r = ch >> 3; int ce = (ch & 7) << 3;
      *(uint4*)&As[r * 64 + ce] = *(const uint4*)&A[(arow0 + r) * II + kt + ce];
      *(uint4*)&Bs[r * 64 + ce] = *(const uint4*)&X[(brow0 + r) * II + kt + ce];
    }
    __syncthreads();
#pragma unroll
    for (int kk = 0; kk < 64; kk += 32){
      bf16x8 a[4], b[4];
#pragma unroll
      for (int mi = 0; mi < 4; ++mi) a[mi] = *(const bf16x8*)&As[(wr * 64 + mi * 16 + (l & 15)) * 64 + kk + (l >> 4) * 8];
#pragma unroll
      for (int ni = 0; ni < 4; ++ni) b[ni] = *(const bf16x8*)&Bs[(wc * 64 + ni * 16 + (l & 15)) * 64 + kk + (l >> 4) * 8];
#pragma unroll
      for (int mi = 0; mi < 4; ++mi)
#pragma unroll
        for (int ni = 0; ni < 4; ++ni)
          acc[mi][ni] = __builtin_amdgcn_mfma_f32_16x16x32_bf16(a[mi], b[ni], acc[mi][ni], 0, 0, 0);
    }
  }
  size_t gxbase = (size_t)d * ((size_t)TT * GG * BB);
#pragma unroll
  for (int mi = 0; mi < 4; ++mi){
    int j0 = jt * 128 + wr * 64 + mi * 16 + ((l >> 4) << 2);
#pragma unroll
    for (int ni = 0; ni < 4; ++ni){
      int m = mt * 128 + wc * 64 + ni * 16 + (l & 15);
      int t = m >> 5, bb = m & 31;
#pragma unroll
      for (int r = 0; r < 4; ++r){
        size_t o = gxbase + ((size_t)(t * GG + j0 + r) * BB + bb);
        float v = s * acc[mi][ni][r];
        if (gx16) gxh[o] = f2bf(v); else gxf[o] = v;
      }
    }
  }
}

// ---------------- persistent recurrent scan, fragment-major exchange ----------------
// 64 blocks (2 dirs x 32 hidden-slices). W_hh slice in REGISTERS (16x bf16x8).
// h exchanged in MFMA B-fragment layout: hfrag[dir][par][arr][kk][lane l x 16B],
// record(arr,kk) lane l = H[arr*16 + (l&15)][kk*32 + (l>>4)*8 .. +8] (bf16).
// Publish: 1KB LDS stage -> wave0 only, 64 coalesced 16B coherent stores.
// Reload: 32x 16B coherent loads/thread straight into MFMA B registers.
template<int GX16>
__global__ __launch_bounds__(256) void k_scan(const unsigned short* __restrict__ qhh,
                                              const float* __restrict__ gxf,
                                              const unsigned short* __restrict__ gxh,
                                              const float* __restrict__ h0,
                                              const float* __restrict__ c0,
                                              const float* __restrict__ bih,
                                              const float* __restrict__ bhh,
                                              const unsigned* __restrict__ scales_raw,
                                              char* __restrict__ hfrag,
                                              unsigned* __restrict__ flags,
                                              int layer,
                                              unsigned short* __restrict__ ys,
                                              float* __restrict__ out){
  __shared__ __align__(16) unsigned short stage[512];   // [2 arr][16 bb][16 klocal]
  int tid = threadIdx.x;
  int d = blockIdx.x >> 5, bi = blockIdx.x & 31;
  int w = tid >> 6, l = tid & 63;
  int ld = layer * 2 + d;
  float s_hh = __uint_as_float(scales_raw[4 + ld]) / 127.0f;

  int hu = l >> 4;
  int hidden = bi * 16 + w * 4 + hu;   // this thread's global hidden index
  int klocal = w * 4 + hu;             // 0..15 within block's slice
  int bb0 = l & 15, bb1 = 16 + bb0;

  char* hfd = hfrag + (size_t)d * 65536;          // 2 parities x 32KB
  unsigned* fl = flags + d * 32;

  // publish-record geometry (wave0 lanes): arr = l>>5, z = (l>>4)&1, bb = l&15
  int p_arr = l >> 5, p_z = (l >> 4) & 1, p_bb = l & 15;
  size_t p_rec = (size_t)p_arr * 16384 + (size_t)(bi >> 1) * 1024
               + (size_t)((2 * (bi & 1) + p_z) * 16 + p_bb) * 16;

  // ---- wave 0: publish h(0) fragments (parity 0), flag = 1 ----
  if (w == 0){
    const float* sp = h0 + ((size_t)ld << 14) + ((size_t)(p_arr * 16 + p_bb) << 9)
                    + bi * 16 + p_z * 8;
    float4 v0 = *(const float4*)sp, v1 = *(const float4*)(sp + 4);
    u32x4 o = {pack2(v0.x, v0.y), pack2(v0.z, v0.w), pack2(v1.x, v1.y), pack2(v1.z, v1.w)};
    st_b128_coh(hfd + p_rec, o);
    WAITV0();
    if (tid == 0)
      __hip_atomic_store(&fl[bi], 1u, __ATOMIC_RELAXED, __HIP_MEMORY_SCOPE_AGENT);
  }

  // ---- per-thread constants: bias, c0, W_hh A-fragments ----
  float bias[4];
#pragma unroll
  for (int gt = 0; gt < 4; ++gt){
    int j = gt * 512 + hidden;
    bias[gt] = bih[(size_t)ld * GG + j] + bhh[(size_t)ld * GG + j];
  }
  float cc0 = c0[((size_t)ld * BB + bb0) * HH + hidden];
  float cc1 = c0[((size_t)ld * BB + bb1) * HH + hidden];

  int rA = w * 16 + (l & 15);
  int koffe = (l >> 4) * 8;
  const unsigned short* qsl = qhh + ((size_t)ld << 20) + ((size_t)bi << 15);
  bf16x8 afrag[16];
#pragma unroll
  for (int kk = 0; kk < 16; ++kk)
    ld_frag(&afrag[kk], qsl + (size_t)rA * 512 + kk * 32 + koffe);

  const float* gxd_f = gxf + (size_t)d * ((size_t)TT * GG * BB);
  const unsigned short* gxd_h = gxh + (size_t)d * ((size_t)TT * GG * BB);

  // prefetch gx for step 0 (in flight until first frag WAITV0)
  float gxv[8]; unsigned gxu[8];
  {
    int t0 = d ? TT - 1 : 0;
    size_t base = (size_t)t0 * GG * BB;
#pragma unroll
    for (int gt = 0; gt < 4; ++gt){
      size_t o = base + (size_t)(gt * 512 + hidden) * BB;
      if (GX16){ ld_ushort(&gxu[gt * 2],     gxd_h + o + bb0);
                 ld_ushort(&gxu[gt * 2 + 1], gxd_h + o + bb1); }
      else     { ld_dword(&gxv[gt * 2],      gxd_f + o + bb0);
                 ld_dword(&gxv[gt * 2 + 1],  gxd_f + o + bb1); }
    }
  }

  for (int s = 0; s < TT; ++s){
    int t = d ? (TT - 1 - s) : s;

    // ---- wait for h(s) fragments published by all 32 peer blocks ----
    if (w == 0 && l < 32){
      unsigned target = (unsigned)(s + 1);
      while (true){
        unsigned v = __hip_atomic_load(&fl[l], __ATOMIC_RELAXED, __HIP_MEMORY_SCOPE_AGENT);
        if (__all((int)(v >= target))) break;
        __builtin_amdgcn_s_sleep(1);
      }
    }
    __syncthreads();   // B2: release all waves; (implicit drain: background stores long done)

    // ---- load B-fragments straight into registers (coherent, coalesced) ----
    const char* pb = hfd + (size_t)(s & 1) * 32768 + (size_t)l * 16;
    bf16x8 b0f[16], b1f[16];
#pragma unroll
    for (int kk = 0; kk < 16; ++kk) ld_frag_coh(&b0f[kk], pb + kk * 1024);
#pragma unroll
    for (int kk = 0; kk < 16; ++kk) ld_frag_coh(&b1f[kk], pb + 16384 + kk * 1024);
    WAITV0();          // frags + gx(s) + (s==0: afrag) resident

    f32x4 acc0 = {0.f, 0.f, 0.f, 0.f}, acc1 = {0.f, 0.f, 0.f, 0.f};
#pragma unroll
    for (int kk = 0; kk < 16; ++kk){
      acc0 = __builtin_amdgcn_mfma_f32_16x16x32_bf16(afrag[kk], b0f[kk], acc0, 0, 0, 0);
      acc1 = __builtin_amdgcn_mfma_f32_16x16x32_bf16(afrag[kk], b1f[kk], acc1, 0, 0, 0);
    }

    float g0[4], g1[4];
#pragma unroll
    for (int gt = 0; gt < 4; ++gt){
      float gx0 = GX16 ? bf2f((unsigned short)gxu[gt * 2])     : gxv[gt * 2];
      float gx1 = GX16 ? bf2f((unsigned short)gxu[gt * 2 + 1]) : gxv[gt * 2 + 1];
      g0[gt] = acc0[gt] * s_hh + gx0 + bias[gt];
      g1[gt] = acc1[gt] * s_hh + gx1 + bias[gt];
    }
    float i0 = sigm(g0[0]), f0 = sigm(g0[1]), G0 = tanh_(g0[2]), o0 = sigm(g0[3]);
    float i1 = sigm(g1[0]), f1 = sigm(g1[1]), G1 = tanh_(g1[2]), o1 = sigm(g1[3]);
    float cn0 = f0 * cc0 + i0 * G0;  cc0 = cn0;
    float cn1 = f1 * cc1 + i1 * G1;  cc1 = cn1;
    float hx0 = o0 * tanh_(cn0);
    float hx1 = o1 * tanh_(cn1);

    // final-step h_n / c_n (drained by post-loop WAITV0)
    if (s == TT - 1){
      st_dword(out + 8388608ull + ((size_t)ld * BB + bb0) * HH + hidden, hx0);
      st_dword(out + 8388608ull + ((size_t)ld * BB + bb1) * HH + hidden, hx1);
      st_dword(out + 8454144ull + ((size_t)ld * BB + bb0) * HH + hidden, cn0);
      st_dword(out + 8454144ull + ((size_t)ld * BB + bb1) * HH + hidden, cn1);
    }

    // ---- stage this block's h-slice in LDS: [arr][bb][klocal] ----
    stage[bb0 * 16 + klocal]       = f2bf(hx0);
    stage[256 + bb0 * 16 + klocal] = f2bf(hx1);
    __syncthreads();   // B1: stage complete

    if (w == 0){
      // publisher: 64 coalesced coherent 16B stores, own-wave ack, flag
      if (s < TT - 1){
        u32x4 v = *(const u32x4*)&stage[p_arr * 256 + p_bb * 16 + p_z * 8];
        st_b128_coh(hfd + (size_t)((s + 1) & 1) * 32768 + p_rec, v);
        WAITV0();
        if (tid == 0)
          __hip_atomic_store(&fl[bi], (unsigned)(s + 2), __ATOMIC_RELAXED, __HIP_MEMORY_SCOPE_AGENT);
      }
    } else if (w == 1){
      // ys writer: 64 coalesced 16B stores (background; drains under next poll)
      int i = tid - 64;
      int arr = i >> 5, bbx = (i >> 1) & 15, half = i & 1;
      u32x4 v = *(const u32x4*)&stage[arr * 256 + bbx * 16 + half * 8];
      st_b128(ys + (((size_t)(t * BB + arr * 16 + bbx)) << 10) + d * 512 + bi * 16 + half * 8, v);
    }

    // gx prefetch for step s+1 (all waves; drains under poll + next frag wait)
    if (s < TT - 1){
      int tn = d ? (TT - 2 - s) : (s + 1);
      size_t base = (size_t)tn * GG * BB;
#pragma unroll
      for (int gt = 0; gt < 4; ++gt){
        size_t o = base + (size_t)(gt * 512 + hidden) * BB;
        if (GX16){ ld_ushort(&gxu[gt * 2],     gxd_h + o + bb0);
                   ld_ushort(&gxu[gt * 2 + 1], gxd_h + o + bb1); }
        else     { ld_dword(&gxv[gt * 2],      gxd_f + o + bb0);
                   ld_dword(&gxv[gt * 2 + 1],  gxd_f + o + bb1); }
      }
    }
  }
  WAITV0();   // drain h_n/c_n and last ys stores
}

// ---------------- layer-1 ys (bf16, [t][b][1024]) -> out (f32, [b][t][1024]) ----------------
__global__ __launch_bounds__(256) void k_out(const unsigned short* __restrict__ ys,
                                             float* __restrict__ out){
  size_t i4 = (size_t)blockIdx.x * 256 + threadIdx.x;
  size_t idx = i4 << 2;
  size_t row = idx >> 10; int c = (int)(idx & 1023);
  int t = (int)(row >> 5), b = (int)(row & 31);
  ushort4 v = *(const ushort4*)&ys[idx];
  float4 o = {bf2f(v.x), bf2f(v.y), bf2f(v.z), bf2f(v.w)};
  *(float4*)&out[(((size_t)b * TT + t) << 10) + c] = o;
}

extern "C" void kernel_launch(void* const* d_in, const int* in_sizes, int n_in,
                              void* d_out, int out_size, void* d_ws, size_t ws_size,
                              hipStream_t stream){
  if (n_in < 7) return;
  const float* x   = (const float*)d_in[0];
  const float* h0  = (const float*)d_in[1];
  const float* c0  = (const float*)d_in[2];
  const float* wih = (const float*)d_in[3];
  const float* whh = (const float*)d_in[4];
  const float* bih = (const float*)d_in[5];
  const float* bhh = (const float*)d_in[6];
  float* out = (float*)d_out;

  char* ws = (char*)d_ws;
  unsigned* flags = (unsigned*)(ws + WS_OFF_FLAGS);
  unsigned* scales = (unsigned*)(ws + WS_OFF_SCALES);
  unsigned short* qih  = (unsigned short*)(ws + WS_OFF_QIH);
  unsigned short* qhh  = (unsigned short*)(ws + WS_OFF_QHH);
  unsigned short* xbuf = (unsigned short*)(ws + WS_OFF_XBUF);
  unsigned short* ys1  = (unsigned short*)(ws + WS_OFF_YS1);
  char* hfrag = ws + WS_OFF_HFRAG;
  float* gxf = (float*)(ws + WS_OFF_GX);
  unsigned short* gxh = (unsigned short*)(ws + WS_OFF_GX);

  size_t need_f32 = WS_OFF_GX + GX_ELEMS * 4ull;
  int gx16 = (ws_size >= need_f32) ? 0 : 1;

  (void)hipMemsetAsync(ws, 0, WS_MEMSET_SPAN, stream);

  k_absmax<<<dim3(32, 8), 256, 0, stream>>>(wih, whh, scales);
  k_quant_ih<<<4096, 256, 0, stream>>>(wih, qih, scales);
  k_quant_hh<<<2048, 256, 0, stream>>>(whh, qhh, scales);
  k_cvtx<<<4096, 256, 0, stream>>>(x, xbuf);

  // layer 0
  k_gemm<<<dim3(64, 16, 2), 256, 0, stream>>>(qih, xbuf, gxf, gxh, gx16, scales, 0);
  if (gx16) k_scan<1><<<64, 256, 0, stream>>>(qhh, gxf, gxh, h0, c0, bih, bhh, scales, hfrag, flags, 0, ys1, out);
  else      k_scan<0><<<64, 256, 0, stream>>>(qhh, gxf, gxh, h0, c0, bih, bhh, scales, hfrag, flags, 0, ys1, out);
  // layer 1
  k_gemm<<<dim3(64, 16, 2), 256, 0, stream>>>(qih + 2ull * GG * II, ys1, gxf, gxh, gx16, scales, 2);
  if (gx16) k_scan<1><<<64, 256, 0, stream>>>(qhh, gxf, gxh, h0, c0, bih, bhh, scales, hfrag, flags + 64, 1, ys1, out);
  else      k_scan<0><<<64, 256, 0, stream>>>(qhh, gxf, gxh, h0, c0, bih, bhh, scales, hfrag, flags + 64, 1, ys1, out);

  k_out<<<8192, 256, 0, stream>>>(ys1, out);

  (void)in_sizes; (void)out_size;
}